// Round 5
// baseline (187.473 us; speedup 1.0000x reference)
//
#include <hip/hip_runtime.h>
#include <math.h>

// Problem constants (from reference setup_inputs)
#define BB 8
#define CC 192
#define HH 128
#define WW 128
#define RPT 8    // rows per thread; block covers 64 rows x 128 cols, grid.y=2 halves

typedef float vf4 __attribute__((ext_vector_type(4)));   // native vector for builtins

__device__ __forceinline__ float col9(float a0, float a1, float a2,
                                      float b0, float b1, float b2,
                                      float c0, float c1, float c2,
                                      float th, const float* kk) {
    float m;
    m = fmaf(th, kk[0], a0);
    m = fmaxf(m, fmaf(th, kk[1], a1));
    m = fmaxf(m, fmaf(th, kk[2], a2));
    m = fmaxf(m, fmaf(th, kk[3], b0));
    m = fmaxf(m, fmaf(th, kk[4], b1));
    m = fmaxf(m, fmaf(th, kk[5], b2));
    m = fmaxf(m, fmaf(th, kk[6], c0));
    m = fmaxf(m, fmaf(th, kk[7], c1));
    m = fmaxf(m, fmaf(th, kk[8], c2));
    return m;
}

__global__ __launch_bounds__(256) void dynmorph_kernel(
    const float* __restrict__ x,      // [B, C, H, W]
    const float* __restrict__ kern,   // [C, 9]
    const float* __restrict__ gw,     // [C]
    const float* __restrict__ gb,     // [C]
    float* __restrict__ out)          // [B, C, H, W]
{
    const int tid  = threadIdx.x;
    const int lane = tid & 63;
    const int wg   = lane & 31;                      // column group: cols 4*wg..4*wg+3
    const int rs   = (tid >> 6) * 2 + (lane >> 5);   // row-stream 0..7
    const int col  = wg * 4;
    const int r0   = blockIdx.y * (RPT * 8) + rs * RPT;

    const int bc = blockIdx.x;                       // b*C + c  (block-uniform)
    const int c  = bc % CC;

    const float* xp = x   + (size_t)bc * (HH * WW);
    float*       op = out + (size_t)bc * (HH * WW);

    // Block-uniform coefficients -> SGPRs (scalar loads)
    float kk[9];
#pragma unroll
    for (int i = 0; i < 9; ++i) kk[i] = kern[c * 9 + i];
    const float gwc = gw[c];
    const float gbc = gb[c];

    // ---- Phase 1: issue ALL 10 row loads; sched_barrier pins them here ----
    vf4 v[RPT + 2];
#pragma unroll
    for (int i = 0; i < RPT + 2; ++i) {
        const int g = r0 - 1 + i;
        if (g >= 0 && g < HH) {
            v[i] = *(const vf4*)(xp + g * WW + col);
        } else {
            v[i] = (vf4)(0.0f);
        }
    }
    __builtin_amdgcn_sched_barrier(0);   // loads may NOT sink below this point

    // ---- Phase 2: halo exchange via wave shuffles ----
    float lf[RPT + 2], rt[RPT + 2];
#pragma unroll
    for (int i = 0; i < RPT + 2; ++i) {
        const float l = __shfl_up(v[i].w, 1);
        const float r = __shfl_down(v[i].x, 1);
        lf[i] = (wg == 0)  ? 0.0f : l;   // w = -1 (zero pad)
        rt[i] = (wg == 31) ? 0.0f : r;   // w = 128 (zero pad)
    }
    __builtin_amdgcn_sched_barrier(0);   // shuffles stay batched up here

    // ---- Phase 3: compute + nontemporal store, fully unrolled ----
#pragma unroll
    for (int g = 0; g < RPT; ++g) {
        const vf4 A = v[g], B = v[g + 1], Cv = v[g + 2];

        const float t0 = __builtin_amdgcn_rcpf(1.0f + __expf(-fmaf(B.x, gwc, gbc)));
        const float t1 = __builtin_amdgcn_rcpf(1.0f + __expf(-fmaf(B.y, gwc, gbc)));
        const float t2 = __builtin_amdgcn_rcpf(1.0f + __expf(-fmaf(B.z, gwc, gbc)));
        const float t3 = __builtin_amdgcn_rcpf(1.0f + __expf(-fmaf(B.w, gwc, gbc)));

        vf4 o;
        o.x = col9(lf[g],   A.x, A.y,
                   lf[g+1], B.x, B.y,
                   lf[g+2], Cv.x, Cv.y, t0, kk);
        o.y = col9(A.x, A.y, A.z,
                   B.x, B.y, B.z,
                   Cv.x, Cv.y, Cv.z, t1, kk);
        o.z = col9(A.y, A.z, A.w,
                   B.y, B.z, B.w,
                   Cv.y, Cv.z, Cv.w, t2, kk);
        o.w = col9(A.z, A.w, rt[g],
                   B.z, B.w, rt[g+1],
                   Cv.z, Cv.w, rt[g+2], t3, kk);

        __builtin_nontemporal_store(o, (vf4*)(op + (r0 + g) * WW + col));
    }
}

extern "C" void kernel_launch(void* const* d_in, const int* in_sizes, int n_in,
                              void* d_out, int out_size, void* d_ws, size_t ws_size,
                              hipStream_t stream) {
    const float* x    = (const float*)d_in[0];
    const float* kern = (const float*)d_in[1];
    const float* gw   = (const float*)d_in[2];
    const float* gb   = (const float*)d_in[3];
    float* out        = (float*)d_out;

    dim3 grid(BB * CC, 2);   // 3072 blocks; each covers 64 rows x 128 cols
    dim3 block(256);
    dynmorph_kernel<<<grid, block, 0, stream>>>(x, kern, gw, gb, out);
}

// Round 6
// 184.190 us; speedup vs baseline: 1.0178x; 1.0178x over previous
//
#include <hip/hip_runtime.h>
#include <math.h>

// Problem constants (from reference setup_inputs)
#define BB 8
#define CC 192
#define HH 128
#define WW 128
#define RPS 16        // rows per row-stream (8 streams x 16 = 128 rows)
#define DPF 6         // prefetch depth (loads in flight per thread)
#define NB  (DPF + 1) // circular buffer slots

typedef float vf4 __attribute__((ext_vector_type(4)));

__device__ __forceinline__ float col9(float a0, float a1, float a2,
                                      float b0, float b1, float b2,
                                      float c0, float c1, float c2,
                                      float th, const float* kk) {
    float m;
    m = fmaf(th, kk[0], a0);
    m = fmaxf(m, fmaf(th, kk[1], a1));
    m = fmaxf(m, fmaf(th, kk[2], a2));
    m = fmaxf(m, fmaf(th, kk[3], b0));
    m = fmaxf(m, fmaf(th, kk[4], b1));
    m = fmaxf(m, fmaf(th, kk[5], b2));
    m = fmaxf(m, fmaf(th, kk[6], c0));
    m = fmaxf(m, fmaf(th, kk[7], c1));
    m = fmaxf(m, fmaf(th, kk[8], c2));
    return m;
}

__global__ __launch_bounds__(256) void dynmorph_kernel(
    const float* __restrict__ x,      // [B, C, H, W]
    const float* __restrict__ kern,   // [C, 9]
    const float* __restrict__ gw,     // [C]
    const float* __restrict__ gb,     // [C]
    float* __restrict__ out)          // [B, C, H, W]
{
    const int tid  = threadIdx.x;
    const int lane = tid & 63;
    const int wg   = lane & 31;                      // column group: cols 4*wg..4*wg+3
    const int rs   = (tid >> 6) * 2 + (lane >> 5);   // row-stream 0..7
    const int col  = wg * 4;
    const int r0   = rs * RPS;                       // first output row of this stream

    const int bc = blockIdx.x;                       // b*C + c  (block-uniform)
    const int c  = bc % CC;

    const float* xp = x   + (size_t)bc * (HH * WW);
    float*       op = out + (size_t)bc * (HH * WW);

    // Block-uniform coefficients -> SGPRs
    float kk[9];
#pragma unroll
    for (int i = 0; i < 9; ++i) kk[i] = kern[c * 9 + i];
    const float gwc = gw[c];
    const float gbc = gb[c];

    // load idx i  <->  global row (r0 - 1 + i), i in [0, RPS+2)
    auto ld = [&](int i) -> vf4 {
        const int g = r0 - 1 + i;
        if (g >= 0 && g < HH) return *(const vf4*)(xp + g * WW + col);
        return (vf4)(0.0f);
    };

    vf4   buf[NB];
    float lfh[RPS + 2], rth[RPS + 2];

    // ---- Prologue: fill the pipe with DPF loads ----
#pragma unroll
    for (int i = 0; i < DPF; ++i) buf[i % NB] = ld(i);
    __builtin_amdgcn_sched_barrier(0);

    // Halos for idx 0,1 (idx 2's halo comes in iteration 0)
#pragma unroll
    for (int i = 0; i < 2; ++i) {
        const vf4 t = buf[i % NB];
        const float l = __shfl_up(t.w, 1);
        const float r = __shfl_down(t.x, 1);
        lfh[i] = (wg == 0)  ? 0.0f : l;
        rth[i] = (wg == 31) ? 0.0f : r;
    }

    // ---- Steady-state: load(g+DPF) ahead of compute(g), every iteration ----
#pragma unroll
    for (int g = 0; g < RPS; ++g) {
        if (g + DPF < RPS + 2) {
            buf[(g + DPF) % NB] = ld(g + DPF);
        }
        __builtin_amdgcn_sched_barrier(0);   // prefetch may not sink below compute

        // Halo for the newest row this iteration consumes (idx g+2)
        {
            const vf4 t = buf[(g + 2) % NB];
            const float l = __shfl_up(t.w, 1);
            const float r = __shfl_down(t.x, 1);
            lfh[g + 2] = (wg == 0)  ? 0.0f : l;
            rth[g + 2] = (wg == 31) ? 0.0f : r;
        }

        const vf4 A  = buf[g % NB];
        const vf4 B  = buf[(g + 1) % NB];
        const vf4 Cv = buf[(g + 2) % NB];

        const float t0 = __builtin_amdgcn_rcpf(1.0f + __expf(-fmaf(B.x, gwc, gbc)));
        const float t1 = __builtin_amdgcn_rcpf(1.0f + __expf(-fmaf(B.y, gwc, gbc)));
        const float t2 = __builtin_amdgcn_rcpf(1.0f + __expf(-fmaf(B.z, gwc, gbc)));
        const float t3 = __builtin_amdgcn_rcpf(1.0f + __expf(-fmaf(B.w, gwc, gbc)));

        vf4 o;
        o.x = col9(lfh[g],   A.x, A.y,
                   lfh[g+1], B.x, B.y,
                   lfh[g+2], Cv.x, Cv.y, t0, kk);
        o.y = col9(A.x, A.y, A.z,
                   B.x, B.y, B.z,
                   Cv.x, Cv.y, Cv.z, t1, kk);
        o.z = col9(A.y, A.z, A.w,
                   B.y, B.z, B.w,
                   Cv.y, Cv.z, Cv.w, t2, kk);
        o.w = col9(A.z, A.w, rth[g],
                   B.z, B.w, rth[g+1],
                   Cv.z, Cv.w, rth[g+2], t3, kk);

        __builtin_nontemporal_store(o, (vf4*)(op + (r0 + g) * WW + col));
    }
}

extern "C" void kernel_launch(void* const* d_in, const int* in_sizes, int n_in,
                              void* d_out, int out_size, void* d_ws, size_t ws_size,
                              hipStream_t stream) {
    const float* x    = (const float*)d_in[0];
    const float* kern = (const float*)d_in[1];
    const float* gw   = (const float*)d_in[2];
    const float* gb   = (const float*)d_in[3];
    float* out        = (float*)d_out;

    dim3 grid(BB * CC);   // 1536 blocks = exactly 6 per CU, one per (b, c) image
    dim3 block(256);
    dynmorph_kernel<<<grid, block, 0, stream>>>(x, kern, gw, gb, out);
}